// Round 2
// baseline (475.393 us; speedup 1.0000x reference)
//
#include <hip/hip_runtime.h>
#include <cstdint>
#include <cstddef>

// Problem constants
constexpr int B = 32, C = 256, H = 32, W = 32;
constexpr int NPTS = B * H * W;          // 32768 points
constexpr int DIM  = 256;                // embedding dim
constexpr int K    = 1024;               // codebook size
constexpr int QELEMS = B * C * H * W;    // 8388608 quantized elements

// x layout [B,C,H,W]: point n = b*1024 + h*32 + w
// x element for (n, c) = x[(n>>10)*262144 + c*1024 + (n & 1023)]

// ---------------- ||e_k||^2 ----------------
__global__ __launch_bounds__(256) void esq_kernel(const float* __restrict__ emb,
                                                  float* __restrict__ esq) {
  const int r = blockIdx.x * 256 + threadIdx.x;   // grid = K/256
  const float4* row = (const float4*)(emb + (size_t)r * DIM);
  float s = 0.f;
#pragma unroll
  for (int i = 0; i < DIM / 4; ++i) {
    float4 v = row[i];
    s = fmaf(v.x, v.x, s); s = fmaf(v.y, v.y, s);
    s = fmaf(v.z, v.z, s); s = fmaf(v.w, v.w, s);
  }
  esq[r] = s;
}

// ---------------- ||x_n||^2 ----------------
// Needed to replicate the reference's fp32 rounding: distances ~256 have
// ulp 3e-5, which quantizes the argmin comparison. Any fp32 xsq within a few
// ulp of the reference's gives the same argmin (grid-multiple shift).
__global__ __launch_bounds__(256) void xsq_kernel(const float* __restrict__ x,
                                                  float* __restrict__ xsq) {
  const int n = blockIdx.x * 256 + threadIdx.x;   // grid = NPTS/256
  const int bb = n >> 10, hw = n & 1023;
  const float* p = x + (size_t)bb * (C * H * W) + hw;
  float s = 0.f;
#pragma unroll 8
  for (int c = 0; c < DIM; ++c) {
    const float v = p[(size_t)c * 1024];
    s = fmaf(v, v, s);
  }
  xsq[n] = s;
}

// ---------------- argmin over codes (register-tiled fp32 GEMM) ----------------
// Block tile: 128 points x 128 codes, 256 threads, 8x8 per-thread outer product.
// grid.x = NPTS/128 n-blocks, grid.y = 4 k-splits (256 codes each = 2 tiles of 128).
// Score replicates the reference bit-structure: fl(fl(xsq+esq) - 2*dot).
__global__ __launch_bounds__(256) void argmin_kernel(
    const float* __restrict__ x, const float* __restrict__ emb,
    const float* __restrict__ esq, const float* __restrict__ xsq,
    float2* __restrict__ part) {
  __shared__ float xs[16][128];   // [c][n]
  __shared__ float es[16][128];   // [c][k]
  __shared__ float red_s[16][128];
  __shared__ int   red_k[16][128];
  __shared__ float xq_s[128];

  const int t  = threadIdx.x;
  const int tx = t & 15;          // n-octet selector
  const int ty = t >> 4;          // k-octet selector
  const int nblk = blockIdx.x * 128;
  const int bb   = nblk >> 10;
  const int nin  = nblk & 1023;
  const float* xbase = x + (size_t)bb * (C * H * W) + nin;

  if (t < 128) xq_s[t] = xsq[nblk + t];
  __syncthreads();
  float xq[8];
#pragma unroll
  for (int j = 0; j < 8; ++j) xq[j] = xq_s[tx * 8 + j];

  float best_s[8];
  int   best_k[8];
#pragma unroll
  for (int j = 0; j < 8; ++j) { best_s[j] = INFINITY; best_k[j] = 0; }

  const int nl  = t & 127, cbh = t >> 7;      // x staging: 128 n x 2 c-phases
  const int ec4 = (t & 3) * 4, ekl = t >> 2;  // e staging: float4 over c, 64 k rows

  for (int kt = 0; kt < 2; ++kt) {
    const int k0 = blockIdx.y * 256 + kt * 128;
    float acc[8][8];
#pragma unroll
    for (int j = 0; j < 8; ++j)
#pragma unroll
      for (int i = 0; i < 8; ++i) acc[j][i] = 0.f;

    for (int c0 = 0; c0 < DIM; c0 += 16) {
      __syncthreads();
      // stage x tile: xs[c][n], coalesced global reads
#pragma unroll
      for (int i = 0; i < 8; ++i) {
        const int c = cbh + 2 * i;
        xs[c][nl] = xbase[(size_t)(c0 + c) * 1024 + nl];
      }
      // stage e tile: es[c][k] via float4 row reads
#pragma unroll
      for (int i = 0; i < 2; ++i) {
        const int k = ekl + 64 * i;
        const float4 e4 = *(const float4*)(emb + (size_t)(k0 + k) * DIM + c0 + ec4);
        es[ec4 + 0][k] = e4.x; es[ec4 + 1][k] = e4.y;
        es[ec4 + 2][k] = e4.z; es[ec4 + 3][k] = e4.w;
      }
      __syncthreads();
#pragma unroll
      for (int c = 0; c < 16; ++c) {
        const float4 xa = *(const float4*)&xs[c][tx * 8];
        const float4 xb = *(const float4*)&xs[c][tx * 8 + 4];
        const float4 ea = *(const float4*)&es[c][ty * 8];
        const float4 eb = *(const float4*)&es[c][ty * 8 + 4];
        const float xv[8] = {xa.x, xa.y, xa.z, xa.w, xb.x, xb.y, xb.z, xb.w};
        const float ev[8] = {ea.x, ea.y, ea.z, ea.w, eb.x, eb.y, eb.z, eb.w};
#pragma unroll
        for (int j = 0; j < 8; ++j)
#pragma unroll
          for (int i = 0; i < 8; ++i)
            acc[j][i] = fmaf(xv[j], ev[i], acc[j][i]);
      }
    }
    // fold: d = fl(fl(xsq+esq) - 2*dot)  (2*acc is exact; fma contraction safe)
#pragma unroll
    for (int i = 0; i < 8; ++i) {
      const int k = k0 + ty * 8 + i;
      const float eq = esq[k];
#pragma unroll
      for (int j = 0; j < 8; ++j) {
        const float t1 = xq[j] + eq;          // rounded add, like the reference
        const float s = t1 - 2.f * acc[j][i]; // single rounding; 2*acc exact
        if (s < best_s[j] || (s == best_s[j] && k < best_k[j])) {
          best_s[j] = s; best_k[j] = k;
        }
      }
    }
  }
  // cross-ty reduction (16 threads share each point), lexicographic tie-break
#pragma unroll
  for (int j = 0; j < 8; ++j) {
    red_s[ty][tx * 8 + j] = best_s[j];
    red_k[ty][tx * 8 + j] = best_k[j];
  }
  __syncthreads();
  if (t < 128) {
    float bs = red_s[0][t]; int bk = red_k[0][t];
#pragma unroll
    for (int y = 1; y < 16; ++y) {
      const float s = red_s[y][t]; const int k = red_k[y][t];
      if (s < bs || (s == bs && k < bk)) { bs = s; bk = k; }
    }
    part[(size_t)(nblk + t) * 4 + blockIdx.y] = make_float2(bs, __int_as_float(bk));
  }
}

// ---------------- reduce k-split partials -> idx, write one-hot ----------------
__global__ __launch_bounds__(256) void scatter_kernel(
    const float2* __restrict__ part, int* __restrict__ idx, float* __restrict__ enc) {
  const int n = blockIdx.x * 256 + threadIdx.x;   // grid = NPTS/256
  float2 p0 = part[(size_t)n * 4 + 0];
  float bs = p0.x; int bk = __float_as_int(p0.y);
#pragma unroll
  for (int h = 1; h < 4; ++h) {
    const float2 p = part[(size_t)n * 4 + h];
    const int k = __float_as_int(p.y);
    if (p.x < bs || (p.x == bs && k < bk)) { bs = p.x; bk = k; }
  }
  idx[n] = bk;
  enc[(size_t)n * K + bk] = 1.0f;   // region pre-zeroed by memset
}

// ---------------- gather quantized + loss ----------------
__global__ __launch_bounds__(256) void quant_loss_kernel(
    const float* __restrict__ x, const float* __restrict__ emb,
    const int* __restrict__ idx, float* __restrict__ outq, float* __restrict__ loss) {
  const int t = threadIdx.x;
  float lsum = 0.f;
#pragma unroll
  for (int i = 0; i < 8; ++i) {
    const int i4 = blockIdx.x * 2048 + i * 256 + t;   // grid = QELEMS/8192
    const int flat = i4 * 4;                           // [B,C,H,W] linear index
    const int hw = flat & 1023;
    const int c  = (flat >> 10) & 255;
    const int bb = flat >> 18;
    const int n  = (bb << 10) + hw;
    const int4 id = *(const int4*)(idx + n);
    const float4 xv = *(const float4*)(x + (size_t)flat);
    const float q0 = emb[(size_t)id.x * DIM + c];
    const float q1 = emb[(size_t)id.y * DIM + c];
    const float q2 = emb[(size_t)id.z * DIM + c];
    const float q3 = emb[(size_t)id.w * DIM + c];
    // outq = d_out+1 is only 4B-aligned -> scalar stores
    outq[flat + 0] = q0; outq[flat + 1] = q1;
    outq[flat + 2] = q2; outq[flat + 3] = q3;
    const float d0 = q0 - xv.x, d1 = q1 - xv.y, d2 = q2 - xv.z, d3 = q3 - xv.w;
    lsum += d0 * d0 + d1 * d1 + d2 * d2 + d3 * d3;
  }
  float s = lsum;
#pragma unroll
  for (int o = 32; o > 0; o >>= 1) s += __shfl_down(s, o, 64);
  __shared__ float lred[4];
  if ((t & 63) == 0) lred[t >> 6] = s;
  __syncthreads();
  if (t == 0) {
    const float tot = (lred[0] + lred[1] + lred[2] + lred[3]) * (1.25f / (float)QELEMS);
    atomicAdd(loss, tot);   // loss = q_latent + 0.25*e_latent = 1.25 * MSE
  }
}

extern "C" void kernel_launch(void* const* d_in, const int* in_sizes, int n_in,
                              void* d_out, int out_size, void* d_ws, size_t ws_size,
                              hipStream_t stream) {
  const float* x   = (const float*)d_in[0];
  const float* emb = (const float*)d_in[1];
  float* out  = (float*)d_out;
  float* loss = out;                       // [1]
  float* outq = out + 1;                   // [8388608], 4B-aligned only
  float* enc  = out + 1 + QELEMS;          // [33554432]

  float*  esq  = (float*)d_ws;                                     // 4 KB
  float*  xsq  = (float*)((char*)d_ws + 4096);                     // 128 KB
  int*    idx  = (int*)((char*)d_ws + 4096 + 131072);              // 128 KB
  float2* part = (float2*)((char*)d_ws + 4096 + 2 * 131072);       // 1 MB

  hipMemsetAsync(enc, 0, (size_t)NPTS * K * sizeof(float), stream);
  hipMemsetAsync(loss, 0, sizeof(float), stream);

  esq_kernel<<<K / 256, 256, 0, stream>>>(emb, esq);
  xsq_kernel<<<NPTS / 256, 256, 0, stream>>>(x, xsq);
  dim3 ag(NPTS / 128, 4);
  argmin_kernel<<<ag, 256, 0, stream>>>(x, emb, esq, xsq, part);
  scatter_kernel<<<NPTS / 256, 256, 0, stream>>>(part, idx, enc);
  quant_loss_kernel<<<QELEMS / 8192, 256, 0, stream>>>(x, emb, idx, outq, loss);
}

// Round 3
// 444.696 us; speedup vs baseline: 1.0690x; 1.0690x over previous
//
#include <hip/hip_runtime.h>
#include <cstdint>
#include <cstddef>

// Problem constants
constexpr int B = 32, C = 256, H = 32, W = 32;
constexpr int NPTS = B * H * W;          // 32768 points
constexpr int DIM  = 256;                // embedding dim
constexpr int K    = 1024;               // codebook size
constexpr int QELEMS = B * C * H * W;    // 8388608 quantized elements
constexpr int CHW = C * H * W;           // 262144

// x layout [B,C,H,W]: point n = b*1024 + h*32 + w
// x element for (n, c) = x[(n>>10)*262144 + c*1024 + (n & 1023)]

// ---------------- ||e_k||^2 ----------------
__global__ __launch_bounds__(256) void esq_kernel(const float* __restrict__ emb,
                                                  float* __restrict__ esq) {
  const int r = blockIdx.x * 256 + threadIdx.x;   // grid = K/256
  const float4* row = (const float4*)(emb + (size_t)r * DIM);
  float s = 0.f;
#pragma unroll
  for (int i = 0; i < DIM / 4; ++i) {
    float4 v = row[i];
    s = fmaf(v.x, v.x, s); s = fmaf(v.y, v.y, s);
    s = fmaf(v.z, v.z, s); s = fmaf(v.w, v.w, s);
  }
  esq[r] = s;
}

// ---------------- ||x_n||^2 ----------------
// Replicates the reference's fp32 rounding structure: distances ~256 have ulp
// 3e-5; any fp32 xsq within a few ulp gives identical argmin (grid shift).
__global__ __launch_bounds__(256) void xsq_kernel(const float* __restrict__ x,
                                                  float* __restrict__ xsq) {
  const int n = blockIdx.x * 256 + threadIdx.x;   // grid = NPTS/256
  const int bb = n >> 10, hw = n & 1023;
  const float* p = x + (size_t)bb * CHW + hw;
  float s = 0.f;
#pragma unroll 8
  for (int c = 0; c < DIM; ++c) {
    const float v = p[(size_t)c * 1024];
    s = fmaf(v, v, s);
  }
  xsq[n] = s;
}

// ---------------- argmin over codes (register-tiled fp32 GEMM) ----------------
// 128 points x 128 codes per (block, kt), 256 threads, 8x8 outer product.
// grid = (NPTS/128, 4 k-splits). Conflict-free LDS:
//  - n-fragments at tx*4 and 64+tx*4  -> b128 reads 2-way (free)
//  - es padded to 132                 -> staging scalar writes 2-way (free)
//  - reduction arrays alias xs/es     -> LDS 17.2 KB
__global__ __launch_bounds__(256) void argmin_kernel(
    const float* __restrict__ x, const float* __restrict__ emb,
    const float* __restrict__ esq, const float* __restrict__ xsq,
    float2* __restrict__ part) {
  __shared__ __align__(16) char smem[17152];
  float (*xs)[128] = (float (*)[128])smem;             // 8192 B
  float (*es)[132] = (float (*)[132])(smem + 8192);    // 8448 B
  float* xq_s      = (float*)(smem + 16640);           // 512 B
  float (*red_s)[128] = (float (*)[128])smem;          // alias (post-compute)
  int   (*red_k)[128] = (int (*)[128])(smem + 8192);   // alias

  const int t  = threadIdx.x;
  const int tx = t & 15;
  const int ty = t >> 4;          // 0..15
  const int nblk = blockIdx.x * 128;
  const int bb   = nblk >> 10;
  const int nin  = nblk & 1023;
  const float* xbase = x + (size_t)bb * CHW + nin;

  if (t < 128) xq_s[t] = xsq[nblk + t];
  __syncthreads();
  float xq[8];
#pragma unroll
  for (int j = 0; j < 8; ++j) {
    const int p = (j < 4) ? (tx * 4 + j) : (64 + tx * 4 + (j - 4));
    xq[j] = xq_s[p];
  }

  float best_s[8];
  int   best_k[8];
#pragma unroll
  for (int j = 0; j < 8; ++j) { best_s[j] = INFINITY; best_k[j] = 0; }

  const int sn4 = (t & 31) * 4;   // xs staging: float4 col
  const int scc = t >> 5;         // xs staging: c (0..7, x2 phases)
  const int ec4 = (t & 3) * 4;    // es staging: float4 over c
  const int ekl = t >> 2;         // es staging: k row (0..63, x2 phases)

  for (int kt = 0; kt < 2; ++kt) {
    const int k0 = blockIdx.y * 256 + kt * 128;
    float acc[8][8];
#pragma unroll
    for (int j = 0; j < 8; ++j)
#pragma unroll
      for (int i = 0; i < 8; ++i) acc[j][i] = 0.f;

    for (int c0 = 0; c0 < DIM; c0 += 16) {
      __syncthreads();
      // stage x tile: xs[c][n], float4 over n, coalesced
#pragma unroll
      for (int i = 0; i < 2; ++i) {
        const int c = scc + 8 * i;
        const float4 v = *(const float4*)&xbase[(size_t)(c0 + c) * 1024 + sn4];
        *(float4*)&xs[c][sn4] = v;
      }
      // stage e tile: es[c][k] via float4 row reads (transpose in LDS)
#pragma unroll
      for (int i = 0; i < 2; ++i) {
        const int k = ekl + 64 * i;
        const float4 e4 = *(const float4*)(emb + (size_t)(k0 + k) * DIM + c0 + ec4);
        es[ec4 + 0][k] = e4.x; es[ec4 + 1][k] = e4.y;
        es[ec4 + 2][k] = e4.z; es[ec4 + 3][k] = e4.w;
      }
      __syncthreads();
#pragma unroll
      for (int c = 0; c < 16; ++c) {
        const float4 xa = *(const float4*)&xs[c][tx * 4];
        const float4 xb = *(const float4*)&xs[c][64 + tx * 4];
        const float4 ea = *(const float4*)&es[c][ty * 8];
        const float4 eb = *(const float4*)&es[c][ty * 8 + 4];
        const float xv[8] = {xa.x, xa.y, xa.z, xa.w, xb.x, xb.y, xb.z, xb.w};
        const float ev[8] = {ea.x, ea.y, ea.z, ea.w, eb.x, eb.y, eb.z, eb.w};
#pragma unroll
        for (int j = 0; j < 8; ++j)
#pragma unroll
          for (int i = 0; i < 8; ++i)
            acc[j][i] = fmaf(xv[j], ev[i], acc[j][i]);
      }
    }
    // fold: d = fl(fl(xsq+esq) - 2*dot); 2*acc exact, single rounding
#pragma unroll
    for (int i = 0; i < 8; ++i) {
      const int k = k0 + ty * 8 + i;
      const float eq = esq[k];
#pragma unroll
      for (int j = 0; j < 8; ++j) {
        const float t1 = xq[j] + eq;
        const float s = t1 - 2.f * acc[j][i];
        if (s < best_s[j] || (s == best_s[j] && k < best_k[j])) {
          best_s[j] = s; best_k[j] = k;
        }
      }
    }
  }
  __syncthreads();   // all xs/es reads done before alias write
#pragma unroll
  for (int j = 0; j < 8; ++j) {
    const int p = (j < 4) ? (tx * 4 + j) : (64 + tx * 4 + (j - 4));
    red_s[ty][p] = best_s[j];
    red_k[ty][p] = best_k[j];
  }
  __syncthreads();
  if (t < 128) {
    float bs = red_s[0][t]; int bk = red_k[0][t];
#pragma unroll
    for (int y = 1; y < 16; ++y) {
      const float s = red_s[y][t]; const int k = red_k[y][t];
      if (s < bs || (s == bs && k < bk)) { bs = s; bk = k; }
    }
    part[(size_t)(nblk + t) * 4 + blockIdx.y] = make_float2(bs, __int_as_float(bk));
  }
}

// ---------------- reduce k-split partials -> idx ----------------
__global__ __launch_bounds__(256) void scatter_kernel(
    const float2* __restrict__ part, int* __restrict__ idx) {
  const int n = blockIdx.x * 256 + threadIdx.x;   // grid = NPTS/256
  float2 p0 = part[(size_t)n * 4 + 0];
  float bs = p0.x; int bk = __float_as_int(p0.y);
#pragma unroll
  for (int h = 1; h < 4; ++h) {
    const float2 p = part[(size_t)n * 4 + h];
    const int k = __float_as_int(p.y);
    if (p.x < bs || (p.x == bs && k < bk)) { bs = p.x; bk = k; }
  }
  idx[n] = bk;
}

// ---------------- one-hot encodings (full coalesced write) ----------------
__global__ __launch_bounds__(256) void enc_kernel(const int* __restrict__ idx,
                                                  float* __restrict__ enc) {
  const size_t e = ((size_t)blockIdx.x * 256 + threadIdx.x) * 4;  // grid = NPTS*K/1024
  const int n  = (int)(e >> 10);
  const int k0 = (int)(e & 1023);
  const int id = idx[n];   // broadcast: one n per wave
#pragma unroll
  for (int j = 0; j < 4; ++j) enc[e + j] = (k0 + j == id) ? 1.f : 0.f;
}

// ---------------- gather quantized + loss (LDS transpose) ----------------
// Block = 32 points x 256 c. Phase 1: vectorized row gathers -> LDS [c][p].
// Phase 2: coalesced x reads / outq writes + loss accumulation.
__global__ __launch_bounds__(256) void quant_loss_kernel(
    const float* __restrict__ x, const float* __restrict__ emb,
    const int* __restrict__ idx, float* __restrict__ outq, float* __restrict__ loss) {
  __shared__ float tile[DIM * 32];   // 32 KB, [c][p]
  const int t = threadIdx.x;
  const int n0 = blockIdx.x * 32;    // grid = NPTS/32 = 1024
  const int bb = n0 >> 10, hw0 = n0 & 1023;
  const int p = t & 31, cseg = t >> 5;   // 8 segs x 32 c

  const int row = idx[n0 + p];
  const float* er = emb + (size_t)row * DIM + cseg * 32;
#pragma unroll
  for (int i = 0; i < 8; ++i) {
    const float4 v = *(const float4*)(er + i * 4);
    const int c = cseg * 32 + i * 4;
    tile[(c + 0) * 32 + p] = v.x;
    tile[(c + 1) * 32 + p] = v.y;
    tile[(c + 2) * 32 + p] = v.z;
    tile[(c + 3) * 32 + p] = v.w;
  }
  __syncthreads();

  float lsum = 0.f;
  const float* xb = x + (size_t)bb * CHW + hw0;
  float* ob = outq + (size_t)bb * CHW + hw0;
#pragma unroll
  for (int i = 0; i < 32; ++i) {
    const int c = cseg + i * 8;
    const float q  = tile[c * 32 + p];
    const float xv = xb[(size_t)c * 1024 + p];
    ob[(size_t)c * 1024 + p] = q;    // outq only 4B-aligned -> scalar, coalesced
    const float d = q - xv;
    lsum = fmaf(d, d, lsum);
  }
  float s = lsum;
#pragma unroll
  for (int o = 32; o > 0; o >>= 1) s += __shfl_down(s, o, 64);
  __shared__ float lred[4];
  if ((t & 63) == 0) lred[t >> 6] = s;
  __syncthreads();
  if (t == 0) {
    const float tot = (lred[0] + lred[1] + lred[2] + lred[3]) * (1.25f / (float)QELEMS);
    atomicAdd(loss, tot);   // loss = q_latent + 0.25*e_latent = 1.25 * MSE
  }
}

extern "C" void kernel_launch(void* const* d_in, const int* in_sizes, int n_in,
                              void* d_out, int out_size, void* d_ws, size_t ws_size,
                              hipStream_t stream) {
  const float* x   = (const float*)d_in[0];
  const float* emb = (const float*)d_in[1];
  float* out  = (float*)d_out;
  float* loss = out;                       // [1]
  float* outq = out + 1;                   // [8388608], 4B-aligned only
  float* enc  = out + 1 + QELEMS;          // [33554432]

  float*  esq  = (float*)d_ws;                                     // 4 KB
  float*  xsq  = (float*)((char*)d_ws + 4096);                     // 128 KB
  int*    idx  = (int*)((char*)d_ws + 4096 + 131072);              // 128 KB
  float2* part = (float2*)((char*)d_ws + 4096 + 2 * 131072);       // 1 MB

  hipMemsetAsync(loss, 0, sizeof(float), stream);

  esq_kernel<<<K / 256, 256, 0, stream>>>(emb, esq);
  xsq_kernel<<<NPTS / 256, 256, 0, stream>>>(x, xsq);
  dim3 ag(NPTS / 128, 4);
  argmin_kernel<<<ag, 256, 0, stream>>>(x, emb, esq, xsq, part);
  scatter_kernel<<<NPTS / 256, 256, 0, stream>>>(part, idx);
  enc_kernel<<<(NPTS * K) / 1024, 256, 0, stream>>>(idx, enc);
  quant_loss_kernel<<<NPTS / 32, 256, 0, stream>>>(x, emb, idx, outq, loss);
}

// Round 4
// 440.689 us; speedup vs baseline: 1.0787x; 1.0091x over previous
//
#include <hip/hip_runtime.h>
#include <cstdint>
#include <cstddef>

// Problem constants
constexpr int B = 32, C = 256, H = 32, W = 32;
constexpr int NPTS = B * H * W;          // 32768 points
constexpr int DIM  = 256;                // embedding dim
constexpr int K    = 1024;               // codebook size
constexpr int QELEMS = B * C * H * W;    // 8388608 quantized elements
constexpr int CHW = C * H * W;           // 262144

// x layout [B,C,H,W]: point n = b*1024 + h*32 + w
// x element for (n, c) = x[(n>>10)*262144 + c*1024 + (n & 1023)]

// Async global->LDS, 16B per lane. LDS dest is wave-uniform base + lane*16.
#define GLD_LDS16(g, l)                                                        \
  __builtin_amdgcn_global_load_lds(                                            \
      (const __attribute__((address_space(1))) unsigned int*)(g),              \
      (__attribute__((address_space(3))) unsigned int*)(l), 16, 0, 0)

// ---------------- prep: embT[c][k] transpose + ||e_k||^2 ----------------
// grid = 16 blocks x 256 thr; block handles 64 codebook rows.
__global__ __launch_bounds__(256) void prep_kernel(const float* __restrict__ emb,
                                                   float* __restrict__ embT,
                                                   float* __restrict__ esq) {
  __shared__ float sums[4][64];
  const int t = threadIdx.x;
  const int k = blockIdx.x * 64 + (t & 63);
  const int seg = t >> 6;                       // 4 segs x 64 c
  const float* er = emb + (size_t)k * DIM + seg * 64;
  float v[64];
  float4* v4 = (float4*)v;
#pragma unroll
  for (int i = 0; i < 16; ++i) v4[i] = *(const float4*)(er + i * 4);
  float s = 0.f;
#pragma unroll
  for (int i = 0; i < 64; ++i) s = fmaf(v[i], v[i], s);
#pragma unroll
  for (int i = 0; i < 64; ++i) embT[(size_t)(seg * 64 + i) * K + k] = v[i];
  sums[seg][t & 63] = s;
  __syncthreads();
  if (t < 64)
    esq[blockIdx.x * 64 + t] =
        ((sums[0][t] + sums[1][t]) + sums[2][t]) + sums[3][t];
}

// ---------------- ||x_n||^2 (float4, per-point chain order preserved) --------
__global__ __launch_bounds__(256) void xsq_kernel(const float* __restrict__ x,
                                                  float* __restrict__ xsq) {
  const int g = blockIdx.x * 256 + threadIdx.x;   // grid = NPTS/1024 = 32
  const int n4 = g * 4;
  const float* p = x + (size_t)(n4 >> 10) * CHW + (n4 & 1023);
  float sx = 0.f, sy = 0.f, sz = 0.f, sw = 0.f;
#pragma unroll 8
  for (int c = 0; c < DIM; ++c) {
    const float4 v = *(const float4*)(p + (size_t)c * 1024);
    sx = fmaf(v.x, v.x, sx); sy = fmaf(v.y, v.y, sy);
    sz = fmaf(v.z, v.z, sz); sw = fmaf(v.w, v.w, sw);
  }
  *(float4*)&xsq[n4] = make_float4(sx, sy, sz, sw);
}

// ---------------- argmin over codes (register-tiled fp32 GEMM) ----------------
// 128 points x 128 codes per (block, kt), 256 threads, 8x8 outer product.
// grid = (NPTS/128, 4 k-splits). Both tiles staged via global_load_lds (16B).
// es[c][k] from embT: e-fragment b128 reads are 16-lane broadcast across all
// 32 banks (conflict-free); x-fragment reads 2-way (free).
__global__ __launch_bounds__(256) void argmin_kernel(
    const float* __restrict__ x, const float* __restrict__ embT,
    const float* __restrict__ esq, const float* __restrict__ xsq,
    float2* __restrict__ part) {
  __shared__ __align__(16) float xs[16][128];
  __shared__ __align__(16) float es[16][128];
  __shared__ float xq_s[128];
  float (*red_s)[128] = xs;                    // alias (post-compute)
  int   (*red_k)[128] = (int (*)[128])es;      // alias

  const int t  = threadIdx.x;
  const int tx = t & 15;
  const int ty = t >> 4;
  const int wv = t >> 6;                // wave id 0..3
  const int lrow = (t >> 5) & 1;        // row within 1KB staging inst
  const int lcol = (t & 31) * 4;        // float col within row
  const int nblk = blockIdx.x * 128;
  const float* xbase = x + (size_t)(nblk >> 10) * CHW + (nblk & 1023);

  if (t < 128) xq_s[t] = xsq[nblk + t];
  __syncthreads();
  float xq[8];
#pragma unroll
  for (int j = 0; j < 8; ++j) {
    const int p = (j < 4) ? (tx * 4 + j) : (64 + tx * 4 + (j - 4));
    xq[j] = xq_s[p];
  }

  float best_s[8]; int best_k[8];
#pragma unroll
  for (int j = 0; j < 8; ++j) { best_s[j] = INFINITY; best_k[j] = 0; }

  for (int kt = 0; kt < 2; ++kt) {
    const int k0 = blockIdx.y * 256 + kt * 128;
    float acc[8][8];
#pragma unroll
    for (int j = 0; j < 8; ++j)
#pragma unroll
      for (int i = 0; i < 8; ++i) acc[j][i] = 0.f;

    for (int c0 = 0; c0 < DIM; c0 += 16) {
      __syncthreads();   // previous tile fully consumed
#pragma unroll
      for (int i = 0; i < 2; ++i) {
        const int r = 4 * wv + 2 * i;          // wave-uniform LDS row base
        GLD_LDS16(xbase + (size_t)(c0 + r + lrow) * 1024 + lcol, &xs[r][0]);
        GLD_LDS16(embT + (size_t)(c0 + r + lrow) * 1024 + k0 + lcol, &es[r][0]);
      }
      __syncthreads();   // vmcnt(0) drain: tile visible to all waves
#pragma unroll
      for (int c = 0; c < 16; ++c) {
        const float4 xa = *(const float4*)&xs[c][tx * 4];
        const float4 xb = *(const float4*)&xs[c][64 + tx * 4];
        const float4 ea = *(const float4*)&es[c][ty * 8];
        const float4 eb = *(const float4*)&es[c][ty * 8 + 4];
        const float xv[8] = {xa.x, xa.y, xa.z, xa.w, xb.x, xb.y, xb.z, xb.w};
        const float ev[8] = {ea.x, ea.y, ea.z, ea.w, eb.x, eb.y, eb.z, eb.w};
#pragma unroll
        for (int j = 0; j < 8; ++j)
#pragma unroll
          for (int i = 0; i < 8; ++i)
            acc[j][i] = fmaf(xv[j], ev[i], acc[j][i]);
      }
    }
    // fold: d = fl(fl(xsq+esq) - 2*dot); 2*acc exact, single rounding
#pragma unroll
    for (int i = 0; i < 8; ++i) {
      const int k = k0 + ty * 8 + i;
      const float eq = esq[k];
#pragma unroll
      for (int j = 0; j < 8; ++j) {
        const float t1 = xq[j] + eq;
        const float s = t1 - 2.f * acc[j][i];
        if (s < best_s[j] || (s == best_s[j] && k < best_k[j])) {
          best_s[j] = s; best_k[j] = k;
        }
      }
    }
  }
  __syncthreads();   // all xs/es reads done before alias write
#pragma unroll
  for (int j = 0; j < 8; ++j) {
    const int p = (j < 4) ? (tx * 4 + j) : (64 + tx * 4 + (j - 4));
    red_s[ty][p] = best_s[j];
    red_k[ty][p] = best_k[j];
  }
  __syncthreads();
  if (t < 128) {
    float bs = red_s[0][t]; int bk = red_k[0][t];
#pragma unroll
    for (int y = 1; y < 16; ++y) {
      const float s = red_s[y][t]; const int k = red_k[y][t];
      if (s < bs || (s == bs && k < bk)) { bs = s; bk = k; }
    }
    part[(size_t)(nblk + t) * 4 + blockIdx.y] = make_float2(bs, __int_as_float(bk));
  }
}

// ------- fused: k-split reduce -> idx, quantized gather+write, loss, one-hot -
// Block = 32 points; grid = NPTS/32 = 1024.
__global__ __launch_bounds__(256) void quant_enc_kernel(
    const float* __restrict__ x, const float* __restrict__ emb,
    const float2* __restrict__ part, float* __restrict__ outq,
    float* __restrict__ enc, float* __restrict__ loss) {
  __shared__ float tile[DIM * 32];   // 32 KB, [c][p]
  __shared__ int ids[32];
  __shared__ float lred[4];
  const int t = threadIdx.x;
  const int n0 = blockIdx.x * 32;
  const int bb = n0 >> 10, hw0 = n0 & 1023;

  // phase 0: reduce 4 k-split partials -> ids (lexicographic tie-break)
  if (t < 32) {
    const float4 a = *(const float4*)&part[(size_t)(n0 + t) * 4];
    const float4 b = *(const float4*)&part[(size_t)(n0 + t) * 4 + 2];
    float bs = a.x; int bk = __float_as_int(a.y);
    { const int k = __float_as_int(a.w);
      if (a.z < bs || (a.z == bs && k < bk)) { bs = a.z; bk = k; } }
    { const int k = __float_as_int(b.y);
      if (b.x < bs || (b.x == bs && k < bk)) { bs = b.x; bk = k; } }
    { const int k = __float_as_int(b.w);
      if (b.z < bs || (b.z == bs && k < bk)) { bs = b.z; bk = k; } }
    ids[t] = bk;
  }
  __syncthreads();

  // phase A: gather 32 codebook rows (vectorized along row) -> LDS transpose
  const int p = t & 31, cseg = t >> 5;   // 8 segs x 32 c
  const int row = ids[p];
  const float* er = emb + (size_t)row * DIM + cseg * 32;
#pragma unroll
  for (int i = 0; i < 8; ++i) {
    const float4 v = *(const float4*)(er + i * 4);
    const int c = cseg * 32 + i * 4;
    tile[(c + 0) * 32 + p] = v.x;
    tile[(c + 1) * 32 + p] = v.y;
    tile[(c + 2) * 32 + p] = v.z;
    tile[(c + 3) * 32 + p] = v.w;
  }
  __syncthreads();

  // phase B: coalesced quantized write + loss accumulation
  float lsum = 0.f;
  const float* xb = x + (size_t)bb * CHW + hw0;
  float* ob = outq + (size_t)bb * CHW + hw0;
#pragma unroll
  for (int i = 0; i < 32; ++i) {
    const int c = cseg + i * 8;
    const float q  = tile[c * 32 + p];
    const float xv = xb[(size_t)c * 1024 + p];
    ob[(size_t)c * 1024 + p] = q;    // outq only 4B-aligned -> scalar, coalesced
    const float d = q - xv;
    lsum = fmaf(d, d, lsum);
  }
  float s = lsum;
#pragma unroll
  for (int o = 32; o > 0; o >>= 1) s += __shfl_down(s, o, 64);
  if ((t & 63) == 0) lred[t >> 6] = s;

  // phase C: one-hot encodings for this block's 32 points (enc only 4B-aligned)
#pragma unroll 4
  for (int r = 0; r < 32; ++r) {
    const int id = ids[r];
    const int kb = t * 4;
    float* eb = enc + (size_t)(n0 + r) * K + kb;
    eb[0] = (kb + 0 == id) ? 1.f : 0.f;
    eb[1] = (kb + 1 == id) ? 1.f : 0.f;
    eb[2] = (kb + 2 == id) ? 1.f : 0.f;
    eb[3] = (kb + 3 == id) ? 1.f : 0.f;
  }

  __syncthreads();
  if (t == 0) {
    const float tot = (lred[0] + lred[1] + lred[2] + lred[3]) * (1.25f / (float)QELEMS);
    atomicAdd(loss, tot);   // loss = q_latent + 0.25*e_latent = 1.25 * MSE
  }
}

extern "C" void kernel_launch(void* const* d_in, const int* in_sizes, int n_in,
                              void* d_out, int out_size, void* d_ws, size_t ws_size,
                              hipStream_t stream) {
  const float* x   = (const float*)d_in[0];
  const float* emb = (const float*)d_in[1];
  float* out  = (float*)d_out;
  float* loss = out;                       // [1]
  float* outq = out + 1;                   // [8388608], 4B-aligned only
  float* enc  = out + 1 + QELEMS;          // [33554432], 4B-aligned only

  float*  embT = (float*)d_ws;                                     // 1 MB
  float*  esq  = (float*)((char*)d_ws + (1 << 20));                // 4 KB
  float*  xsq  = (float*)((char*)d_ws + (1 << 20) + 4096);         // 128 KB
  float2* part = (float2*)((char*)d_ws + (1 << 20) + 4096 + 131072); // 1 MB

  hipMemsetAsync(loss, 0, sizeof(float), stream);

  prep_kernel<<<K / 64, 256, 0, stream>>>(emb, embT, esq);
  xsq_kernel<<<NPTS / 1024, 256, 0, stream>>>(x, xsq);
  dim3 ag(NPTS / 128, 4);
  argmin_kernel<<<ag, 256, 0, stream>>>(x, embT, esq, xsq, part);
  quant_enc_kernel<<<NPTS / 32, 256, 0, stream>>>(x, emb, part, outq, enc, loss);
}

// Round 5
// 415.175 us; speedup vs baseline: 1.1450x; 1.0615x over previous
//
#include <hip/hip_runtime.h>
#include <cstdint>
#include <cstddef>

// Problem constants
constexpr int B = 32, C = 256, H = 32, W = 32;
constexpr int NPTS = B * H * W;          // 32768 points
constexpr int DIM  = 256;                // embedding dim
constexpr int K    = 1024;               // codebook size
constexpr int QELEMS = B * C * H * W;    // 8388608 quantized elements
constexpr int CHW = C * H * W;           // 262144

typedef __attribute__((ext_vector_type(8))) short s8v;    // 8 bf16 (4 VGPRs)
typedef __attribute__((ext_vector_type(4))) float f32x4;  // MFMA acc

// Async global->LDS, 16B per lane. LDS dest is wave-uniform base + lane*16.
#define GLD_LDS16(g, l)                                                        \
  __builtin_amdgcn_global_load_lds(                                            \
      (const __attribute__((address_space(1))) unsigned int*)(g),              \
      (__attribute__((address_space(3))) unsigned int*)(l), 16, 0, 0)

__device__ __forceinline__ unsigned short f2bf(float f) {  // RNE fp32->bf16
  unsigned u = __float_as_uint(f);
  return (unsigned short)((u + 0x7FFFu + ((u >> 16) & 1u)) >> 16);
}

// ---------------- eprep: ehi[k][c] bf16 + ||e_k||^2 (R4 esq chain) ----------
__global__ __launch_bounds__(256) void eprep_kernel(const float* __restrict__ emb,
                                                    unsigned short* __restrict__ ehi,
                                                    float* __restrict__ esq) {
  __shared__ float sums[4][64];
  const int t = threadIdx.x;
  const int k = blockIdx.x * 64 + (t & 63);   // grid = K/64
  const int seg = t >> 6;                     // 4 segs x 64 c
  const float* er = emb + (size_t)k * DIM + seg * 64;
  float v[64];
  float4* v4 = (float4*)v;
#pragma unroll
  for (int i = 0; i < 16; ++i) v4[i] = *(const float4*)(er + i * 4);
  float s = 0.f;
#pragma unroll
  for (int i = 0; i < 64; ++i) s = fmaf(v[i], v[i], s);
  unsigned short* eo = ehi + (size_t)k * DIM + seg * 64;
#pragma unroll
  for (int i = 0; i < 8; ++i) {
    unsigned short h[8];
#pragma unroll
    for (int j = 0; j < 8; ++j) h[j] = f2bf(v[i * 8 + j]);
    *(s8v*)(eo + i * 8) = *(s8v*)h;
  }
  sums[seg][t & 63] = s;
  __syncthreads();
  if (t < 64)
    esq[blockIdx.x * 64 + t] =
        ((sums[0][t] + sums[1][t]) + sums[2][t]) + sums[3][t];
}

// ---------------- xprep: xhi[n][c] bf16 (transposed) + ||x_n||^2 ------------
// xsq chain is bit-identical to R2-R4 (fp32 fmaf, c ascending, per point).
__global__ __launch_bounds__(256) void xprep_kernel(const float* __restrict__ x,
                                                    unsigned short* __restrict__ xhi,
                                                    float* __restrict__ xsq) {
  __shared__ float xls[DIM][64];   // 64 KB, [c][p]
  const int t = threadIdx.x;
  const int n0 = blockIdx.x * 64;            // grid = NPTS/64 = 512
  const int bb = n0 >> 10, hw0 = n0 & 1023;
  const int p = t & 63, cs = t >> 6;
  const float* xb = x + (size_t)bb * CHW + hw0;
#pragma unroll 8
  for (int r = 0; r < 64; ++r) {
    const int c = r * 4 + cs;
    xls[c][p] = xb[(size_t)c * 1024 + p];
  }
  __syncthreads();
  if (t < 64) {
    float s = 0.f;
#pragma unroll 8
    for (int c = 0; c < 256; ++c) {
      const float v = xls[c][t];
      s = fmaf(v, v, s);
    }
    xsq[n0 + t] = s;
  }
  const int p2 = t >> 2, cb = (t & 3) * 64;
  unsigned short* xo = xhi + (size_t)(n0 + p2) * DIM + cb;
#pragma unroll
  for (int i = 0; i < 8; ++i) {
    unsigned short h[8];
#pragma unroll
    for (int j = 0; j < 8; ++j) h[j] = f2bf(xls[cb + i * 8 + j][p2]);
    *(s8v*)(xo + i * 8) = *(s8v*)h;
  }
}

// ---------------- coarse argmin: bf16 MFMA + candidate emission -------------
// Block: 128n x 128k, 4 waves (2x2), wave tile 64x64 = 4x4 MFMA 16x16x32.
// grid = (NPTS/128, 8 k-splits). Margin M=1e-3 (~18 sigma of bf16-split error)
// guarantees the exact winner is emitted (Bernstein tail ~e-63).
constexpr float MARGIN = 1e-3f;
__global__ __launch_bounds__(256) void coarse_kernel(
    const unsigned short* __restrict__ xhi, const unsigned short* __restrict__ ehi,
    const float* __restrict__ esq, const float* __restrict__ xsq,
    float* __restrict__ part, unsigned int* __restrict__ cand) {
  __shared__ __align__(16) unsigned short xs[128][32];   // 8 KB
  __shared__ __align__(16) unsigned short es[128][32];   // 8 KB
  __shared__ float xsq_s[128], esq_s[128], thr_s[128];
  __shared__ unsigned long long red2[2][128];
  __shared__ unsigned int cntL[128];

  const int t = threadIdx.x;
  const int lane = t & 63, w = t >> 6;
  const int wn = (w & 1) * 64, wk = (w >> 1) * 64;
  const int col = lane & 15, quad = lane >> 4;
  const int nblk = blockIdx.x * 128;
  const int kblk = blockIdx.y * 128;

  if (t < 128) {
    xsq_s[t] = xsq[nblk + t];
    esq_s[t] = esq[kblk + t];
    cntL[t] = 0u;
  }

  f32x4 acc[4][4];
#pragma unroll
  for (int i = 0; i < 4; ++i)
#pragma unroll
    for (int j = 0; j < 4; ++j) acc[i][j] = (f32x4){0.f, 0.f, 0.f, 0.f};

  const int gl_row = lane >> 2;        // row within 16-row staging inst
  const int gl_c   = (lane & 3) * 8;   // bf16 col offset

  for (int c0 = 0; c0 < DIM; c0 += 32) {
    __syncthreads();   // previous tile fully consumed (drains lgkm+vm)
#pragma unroll
    for (int i = 0; i < 2; ++i) {
      const int inst = w + 4 * i;                 // wave-uniform
      const int row = inst * 16 + gl_row;
      GLD_LDS16(xhi + (size_t)(nblk + row) * DIM + c0 + gl_c, &xs[inst * 16][0]);
      GLD_LDS16(ehi + (size_t)(kblk + row) * DIM + c0 + gl_c, &es[inst * 16][0]);
    }
    __syncthreads();   // vmcnt(0): tiles visible
    s8v a[4], b[4];
#pragma unroll
    for (int ti = 0; ti < 4; ++ti)
      a[ti] = *(const s8v*)&xs[wn + ti * 16 + col][quad * 8];
#pragma unroll
    for (int tj = 0; tj < 4; ++tj)
      b[tj] = *(const s8v*)&es[wk + tj * 16 + col][quad * 8];
#pragma unroll
    for (int ti = 0; ti < 4; ++ti)
#pragma unroll
      for (int tj = 0; tj < 4; ++tj)
        acc[ti][tj] = __builtin_amdgcn_mfma_f32_16x16x32_bf16(
            a[ti], b[tj], acc[ti][tj], 0, 0, 0);
  }

  // fold: per-thread per-n packed (d,k) min over its 4 k-tiles
  unsigned long long nmin[4][4];
#pragma unroll
  for (int ti = 0; ti < 4; ++ti)
#pragma unroll
    for (int r = 0; r < 4; ++r) nmin[ti][r] = ~0ULL;
#pragma unroll
  for (int ti = 0; ti < 4; ++ti)
#pragma unroll
    for (int tj = 0; tj < 4; ++tj) {
      const int krel = wk + tj * 16 + col;
      const float eq = esq_s[krel];
#pragma unroll
      for (int r = 0; r < 4; ++r) {
        const int nl = wn + ti * 16 + quad * 4 + r;
        const float d = (xsq_s[nl] + eq) - 2.f * acc[ti][tj][r];
        const unsigned long long key =
            ((unsigned long long)__float_as_uint(d) << 32) |
            (unsigned)(kblk + krel);
        if (key < nmin[ti][r]) nmin[ti][r] = key;   // d>0 -> uint-monotone
      }
    }
  // butterfly over the 16 cols (stays within quad)
#pragma unroll
  for (int o = 1; o < 16; o <<= 1)
#pragma unroll
    for (int ti = 0; ti < 4; ++ti)
#pragma unroll
      for (int r = 0; r < 4; ++r) {
        const unsigned long long v = __shfl_xor(nmin[ti][r], o, 64);
        if (v < nmin[ti][r]) nmin[ti][r] = v;
      }
  if (col == 0) {
#pragma unroll
    for (int ti = 0; ti < 4; ++ti)
#pragma unroll
      for (int r = 0; r < 4; ++r)
        red2[w >> 1][wn + ti * 16 + quad * 4 + r] = nmin[ti][r];
  }
  __syncthreads();
  if (t < 128) {
    const unsigned long long m0 = red2[0][t], m1 = red2[1][t];
    const unsigned long long m = (m1 < m0) ? m1 : m0;
    const float dmin = __uint_as_float((unsigned)(m >> 32));
    part[(size_t)(nblk + t) * 8 + blockIdx.y] = dmin;   // split-min
    thr_s[t] = dmin + MARGIN;
  }
  __syncthreads();
  // emission: all k with coarse d <= split_min + M
#pragma unroll
  for (int ti = 0; ti < 4; ++ti)
#pragma unroll
    for (int tj = 0; tj < 4; ++tj) {
      const int krel = wk + tj * 16 + col;
      const float eq = esq_s[krel];
#pragma unroll
      for (int r = 0; r < 4; ++r) {
        const int nl = wn + ti * 16 + quad * 4 + r;
        const float d = (xsq_s[nl] + eq) - 2.f * acc[ti][tj][r];
        if (d <= thr_s[nl]) {
          const unsigned slot = atomicAdd(&cntL[nl], 1u);
          if (slot < 4u)
            cand[((size_t)(nblk + nl) * 8 + blockIdx.y) * 4 + slot] =
                (unsigned)(kblk + krel);
        }
      }
    }
  __syncthreads();
  if (t < 128) {
    unsigned c = cntL[t];
    const size_t base = ((size_t)(nblk + t) * 8 + blockIdx.y) * 4;
    if (c > 4u) { cand[base + 3] = 0xFFFFFFFEu; c = 3u; }  // overflow -> rescan
    for (unsigned s = c; s < 4u; ++s) cand[base + s] = 0xFFFFFFFFu;
  }
}

// ---------------- resolve: exact fp32 rescoring of candidates -> idx --------
// Scoring is bit-identical to R2-R4's (fmaf chain c ascending,
// fl(fl(xsq+esq) - 2*dot), lowest-k tie-break) -> same argmin as R4 (passed).
__global__ __launch_bounds__(256) void resolve_kernel(
    const float* __restrict__ x, const float* __restrict__ emb,
    const float* __restrict__ esq, const float* __restrict__ xsq,
    const float* __restrict__ part, const unsigned int* __restrict__ cand,
    int* __restrict__ idx) {
  const int n = blockIdx.x * 256 + threadIdx.x;   // grid = NPTS/256
  const float* xp = x + (size_t)(n >> 10) * CHW + (n & 1023);
  const float xq = xsq[n];
  float4 p0 = *(const float4*)&part[(size_t)n * 8];
  float4 p1 = *(const float4*)&part[(size_t)n * 8 + 4];
  const float pv[8] = {p0.x, p0.y, p0.z, p0.w, p1.x, p1.y, p1.z, p1.w};
  float g = pv[0];
#pragma unroll
  for (int s = 1; s < 8; ++s) g = fminf(g, pv[s]);
  const float thr = g + MARGIN;

  float bd = INFINITY; int bk = K;
  auto score = [&](int k) {
    const float* er = emb + (size_t)k * DIM;
    float dot = 0.f;
#pragma unroll 4
    for (int c4 = 0; c4 < DIM; c4 += 4) {
      const float4 e4 = *(const float4*)(er + c4);
      dot = fmaf(xp[(size_t)(c4 + 0) * 1024], e4.x, dot);
      dot = fmaf(xp[(size_t)(c4 + 1) * 1024], e4.y, dot);
      dot = fmaf(xp[(size_t)(c4 + 2) * 1024], e4.z, dot);
      dot = fmaf(xp[(size_t)(c4 + 3) * 1024], e4.w, dot);
    }
    const float t1 = xq + esq[k];
    const float d = t1 - 2.f * dot;
    if (d < bd || (d == bd && k < bk)) { bd = d; bk = k; }
  };

  for (int s = 0; s < 8; ++s) {
    if (pv[s] > thr) continue;          // split can't contain the winner
    const uint4 cs = *(const uint4*)&cand[((size_t)n * 8 + s) * 4];
    const unsigned ks[4] = {cs.x, cs.y, cs.z, cs.w};
    bool ovf = false;
#pragma unroll
    for (int i = 0; i < 4; ++i) {
      if (ks[i] == 0xFFFFFFFFu) continue;
      if (ks[i] == 0xFFFFFFFEu) { ovf = true; continue; }
      score((int)ks[i]);
    }
    if (ovf)
      for (int k = s * 128; k < s * 128 + 128; ++k) score(k);
  }
  idx[n] = bk;
}

// ------- fused: quantized gather+write, loss, one-hot (R4 structure) --------
__global__ __launch_bounds__(256) void quant_enc_kernel(
    const float* __restrict__ x, const float* __restrict__ emb,
    const int* __restrict__ idx, float* __restrict__ outq,
    float* __restrict__ enc, float* __restrict__ loss) {
  __shared__ float tile[DIM * 32];   // 32 KB, [c][p]
  __shared__ int ids[32];
  __shared__ float lred[4];
  const int t = threadIdx.x;
  const int n0 = blockIdx.x * 32;    // grid = NPTS/32 = 1024
  const int bb = n0 >> 10, hw0 = n0 & 1023;

  if (t < 32) ids[t] = idx[n0 + t];
  __syncthreads();

  const int p = t & 31, cseg = t >> 5;
  const int row = ids[p];
  const float* er = emb + (size_t)row * DIM + cseg * 32;
#pragma unroll
  for (int i = 0; i < 8; ++i) {
    const float4 v = *(const float4*)(er + i * 4);
    const int c = cseg * 32 + i * 4;
    tile[(c + 0) * 32 + p] = v.x;
    tile[(c + 1) * 32 + p] = v.y;
    tile[(c + 2) * 32 + p] = v.z;
    tile[(c + 3) * 32 + p] = v.w;
  }
  __syncthreads();

  float lsum = 0.f;
  const float* xb = x + (size_t)bb * CHW + hw0;
  float* ob = outq + (size_t)bb * CHW + hw0;
#pragma unroll
  for (int i = 0; i < 32; ++i) {
    const int c = cseg + i * 8;
    const float q  = tile[c * 32 + p];
    const float xv = xb[(size_t)c * 1024 + p];
    ob[(size_t)c * 1024 + p] = q;    // outq only 4B-aligned -> scalar, coalesced
    const float d = q - xv;
    lsum = fmaf(d, d, lsum);
  }
  float s = lsum;
#pragma unroll
  for (int o = 32; o > 0; o >>= 1) s += __shfl_down(s, o, 64);
  if ((t & 63) == 0) lred[t >> 6] = s;

#pragma unroll 4
  for (int r = 0; r < 32; ++r) {
    const int id = ids[r];
    const int kb = t * 4;
    float* eb = enc + (size_t)(n0 + r) * K + kb;
    eb[0] = (kb + 0 == id) ? 1.f : 0.f;
    eb[1] = (kb + 1 == id) ? 1.f : 0.f;
    eb[2] = (kb + 2 == id) ? 1.f : 0.f;
    eb[3] = (kb + 3 == id) ? 1.f : 0.f;
  }

  __syncthreads();
  if (t == 0) {
    const float tot = (lred[0] + lred[1] + lred[2] + lred[3]) * (1.25f / (float)QELEMS);
    atomicAdd(loss, tot);   // loss = q_latent + 0.25*e_latent = 1.25 * MSE
  }
}

extern "C" void kernel_launch(void* const* d_in, const int* in_sizes, int n_in,
                              void* d_out, int out_size, void* d_ws, size_t ws_size,
                              hipStream_t stream) {
  const float* x   = (const float*)d_in[0];
  const float* emb = (const float*)d_in[1];
  float* out  = (float*)d_out;
  float* loss = out;                       // [1]
  float* outq = out + 1;                   // [8388608], 4B-aligned only
  float* enc  = out + 1 + QELEMS;          // [33554432], 4B-aligned only

  char* ws = (char*)d_ws;
  unsigned short* ehi  = (unsigned short*)ws;                  // 512 KB
  float*          esq  = (float*)(ws + 524288);                // 4 KB
  float*          xsq  = (float*)(ws + 528384);                // 128 KB
  int*            idx  = (int*)(ws + 659456);                  // 128 KB
  float*          part = (float*)(ws + 790528);                // 1 MB
  unsigned int*   cand = (unsigned int*)(ws + 1839104);        // 4 MB
  unsigned short* xhi  = (unsigned short*)(ws + 6033408);      // 16 MB
  // total ws use: ~22.8 MB

  hipMemsetAsync(loss, 0, sizeof(float), stream);

  eprep_kernel<<<K / 64, 256, 0, stream>>>(emb, ehi, esq);
  xprep_kernel<<<NPTS / 64, 256, 0, stream>>>(x, xhi, xsq);
  dim3 cg(NPTS / 128, 8);
  coarse_kernel<<<cg, 256, 0, stream>>>(xhi, ehi, esq, xsq, part, cand);
  resolve_kernel<<<NPTS / 256, 256, 0, stream>>>(x, emb, esq, xsq, part, cand, idx);
  quant_enc_kernel<<<NPTS / 32, 256, 0, stream>>>(x, emb, idx, outq, enc, loss);
}

// Round 6
// 300.610 us; speedup vs baseline: 1.5814x; 1.3811x over previous
//
#include <hip/hip_runtime.h>
#include <cstdint>
#include <cstddef>

// Problem constants
constexpr int B = 32, C = 256, H = 32, W = 32;
constexpr int NPTS = B * H * W;          // 32768 points
constexpr int DIM  = 256;                // embedding dim
constexpr int K    = 1024;               // codebook size
constexpr int QELEMS = B * C * H * W;    // 8388608 quantized elements
constexpr int CHW = C * H * W;           // 262144

typedef __attribute__((ext_vector_type(8))) short s8v;    // 8 bf16 (4 VGPRs)
typedef __attribute__((ext_vector_type(4))) float f32x4;  // MFMA acc

// Async global->LDS, 16B per lane. LDS dest is wave-uniform base + lane*16.
#define GLD_LDS16(g, l)                                                        \
  __builtin_amdgcn_global_load_lds(                                            \
      (const __attribute__((address_space(1))) unsigned int*)(g),              \
      (__attribute__((address_space(3))) unsigned int*)(l), 16, 0, 0)

__device__ __forceinline__ unsigned short f2bf(float f) {  // RNE fp32->bf16
  unsigned u = __float_as_uint(f);
  return (unsigned short)((u + 0x7FFFu + ((u >> 16) & 1u)) >> 16);
}

// ---------------- eprep: ehi[k][c] bf16 + ||e_k||^2 (R4 esq chain) ----------
__global__ __launch_bounds__(256) void eprep_kernel(const float* __restrict__ emb,
                                                    unsigned short* __restrict__ ehi,
                                                    float* __restrict__ esq) {
  __shared__ float sums[4][64];
  const int t = threadIdx.x;
  const int k = blockIdx.x * 64 + (t & 63);   // grid = K/64
  const int seg = t >> 6;                     // 4 segs x 64 c
  const float* er = emb + (size_t)k * DIM + seg * 64;
  float v[64];
  float4* v4 = (float4*)v;
#pragma unroll
  for (int i = 0; i < 16; ++i) v4[i] = *(const float4*)(er + i * 4);
  float s = 0.f;
#pragma unroll
  for (int i = 0; i < 64; ++i) s = fmaf(v[i], v[i], s);
  unsigned short* eo = ehi + (size_t)k * DIM + seg * 64;
#pragma unroll
  for (int i = 0; i < 8; ++i) {
    unsigned short h[8];
#pragma unroll
    for (int j = 0; j < 8; ++j) h[j] = f2bf(v[i * 8 + j]);
    *(s8v*)(eo + i * 8) = *(s8v*)h;
  }
  sums[seg][t & 63] = s;
  __syncthreads();
  if (t < 64)
    esq[blockIdx.x * 64 + t] =
        ((sums[0][t] + sums[1][t]) + sums[2][t]) + sums[3][t];
}

// ---------------- xprep: xhi[n][c] bf16 (transposed) + ||x_n||^2 ------------
// xsq chain is bit-identical to R2-R5 (fp32 fmaf, c ascending, per point).
__global__ __launch_bounds__(256) void xprep_kernel(const float* __restrict__ x,
                                                    unsigned short* __restrict__ xhi,
                                                    float* __restrict__ xsq) {
  __shared__ float xls[DIM][64];   // 64 KB, [c][p]
  const int t = threadIdx.x;
  const int n0 = blockIdx.x * 64;            // grid = NPTS/64 = 512
  const int bb = n0 >> 10, hw0 = n0 & 1023;
  const int p = t & 63, cs = t >> 6;
  const float* xb = x + (size_t)bb * CHW + hw0;
#pragma unroll 8
  for (int r = 0; r < 64; ++r) {
    const int c = r * 4 + cs;
    xls[c][p] = xb[(size_t)c * 1024 + p];
  }
  __syncthreads();
  if (t < 64) {
    float s = 0.f;
#pragma unroll 8
    for (int c = 0; c < 256; ++c) {
      const float v = xls[c][t];
      s = fmaf(v, v, s);
    }
    xsq[n0 + t] = s;
  }
  const int p2 = t >> 2, cb = (t & 3) * 64;
  unsigned short* xo = xhi + (size_t)(n0 + p2) * DIM + cb;
#pragma unroll
  for (int i = 0; i < 8; ++i) {
    unsigned short h[8];
#pragma unroll
    for (int j = 0; j < 8; ++j) h[j] = f2bf(xls[cb + i * 8 + j][p2]);
    *(s8v*)(xo + i * 8) = *(s8v*)h;
  }
}

// ---------------- coarse argmin: bf16 MFMA + candidate emission -------------
// Block: 128n x 128k, 4 waves (2x2), wave tile 64x64 = 4x4 MFMA 16x16x32.
// grid = (NPTS/128, 8 k-splits). Margin M=1e-3 (~18 sigma of bf16-split error)
// guarantees the exact winner is emitted (Bernstein tail ~e-63).
constexpr float MARGIN = 1e-3f;
__global__ __launch_bounds__(256) void coarse_kernel(
    const unsigned short* __restrict__ xhi, const unsigned short* __restrict__ ehi,
    const float* __restrict__ esq, const float* __restrict__ xsq,
    float* __restrict__ part, unsigned int* __restrict__ cand) {
  __shared__ __align__(16) unsigned short xs[128][32];   // 8 KB
  __shared__ __align__(16) unsigned short es[128][32];   // 8 KB
  __shared__ float xsq_s[128], esq_s[128], thr_s[128];
  __shared__ unsigned long long red2[2][128];
  __shared__ unsigned int cntL[128];

  const int t = threadIdx.x;
  const int lane = t & 63, w = t >> 6;
  const int wn = (w & 1) * 64, wk = (w >> 1) * 64;
  const int col = lane & 15, quad = lane >> 4;
  const int nblk = blockIdx.x * 128;
  const int kblk = blockIdx.y * 128;

  if (t < 128) {
    xsq_s[t] = xsq[nblk + t];
    esq_s[t] = esq[kblk + t];
    cntL[t] = 0u;
  }

  f32x4 acc[4][4];
#pragma unroll
  for (int i = 0; i < 4; ++i)
#pragma unroll
    for (int j = 0; j < 4; ++j) acc[i][j] = (f32x4){0.f, 0.f, 0.f, 0.f};

  const int gl_row = lane >> 2;        // row within 16-row staging inst
  const int gl_c   = (lane & 3) * 8;   // bf16 col offset

  for (int c0 = 0; c0 < DIM; c0 += 32) {
    __syncthreads();   // previous tile fully consumed (drains lgkm+vm)
#pragma unroll
    for (int i = 0; i < 2; ++i) {
      const int inst = w + 4 * i;                 // wave-uniform
      const int row = inst * 16 + gl_row;
      GLD_LDS16(xhi + (size_t)(nblk + row) * DIM + c0 + gl_c, &xs[inst * 16][0]);
      GLD_LDS16(ehi + (size_t)(kblk + row) * DIM + c0 + gl_c, &es[inst * 16][0]);
    }
    __syncthreads();   // vmcnt(0): tiles visible
    s8v a[4], b[4];
#pragma unroll
    for (int ti = 0; ti < 4; ++ti)
      a[ti] = *(const s8v*)&xs[wn + ti * 16 + col][quad * 8];
#pragma unroll
    for (int tj = 0; tj < 4; ++tj)
      b[tj] = *(const s8v*)&es[wk + tj * 16 + col][quad * 8];
#pragma unroll
    for (int ti = 0; ti < 4; ++ti)
#pragma unroll
      for (int tj = 0; tj < 4; ++tj)
        acc[ti][tj] = __builtin_amdgcn_mfma_f32_16x16x32_bf16(
            a[ti], b[tj], acc[ti][tj], 0, 0, 0);
  }

  // fold: per-thread per-n packed (d,k) min over its 4 k-tiles
  unsigned long long nmin[4][4];
#pragma unroll
  for (int ti = 0; ti < 4; ++ti)
#pragma unroll
    for (int r = 0; r < 4; ++r) nmin[ti][r] = ~0ULL;
#pragma unroll
  for (int ti = 0; ti < 4; ++ti)
#pragma unroll
    for (int tj = 0; tj < 4; ++tj) {
      const int krel = wk + tj * 16 + col;
      const float eq = esq_s[krel];
#pragma unroll
      for (int r = 0; r < 4; ++r) {
        const int nl = wn + ti * 16 + quad * 4 + r;
        const float d = (xsq_s[nl] + eq) - 2.f * acc[ti][tj][r];
        const unsigned long long key =
            ((unsigned long long)__float_as_uint(d) << 32) |
            (unsigned)(kblk + krel);
        if (key < nmin[ti][r]) nmin[ti][r] = key;   // d>0 -> uint-monotone
      }
    }
  // butterfly over the 16 cols (stays within quad)
#pragma unroll
  for (int o = 1; o < 16; o <<= 1)
#pragma unroll
    for (int ti = 0; ti < 4; ++ti)
#pragma unroll
      for (int r = 0; r < 4; ++r) {
        const unsigned long long v = __shfl_xor(nmin[ti][r], o, 64);
        if (v < nmin[ti][r]) nmin[ti][r] = v;
      }
  if (col == 0) {
#pragma unroll
    for (int ti = 0; ti < 4; ++ti)
#pragma unroll
      for (int r = 0; r < 4; ++r)
        red2[w >> 1][wn + ti * 16 + quad * 4 + r] = nmin[ti][r];
  }
  __syncthreads();
  if (t < 128) {
    const unsigned long long m0 = red2[0][t], m1 = red2[1][t];
    const unsigned long long m = (m1 < m0) ? m1 : m0;
    const float dmin = __uint_as_float((unsigned)(m >> 32));
    part[(size_t)(nblk + t) * 8 + blockIdx.y] = dmin;   // split-min
    thr_s[t] = dmin + MARGIN;
  }
  __syncthreads();
  // emission: all k with coarse d <= split_min + M
#pragma unroll
  for (int ti = 0; ti < 4; ++ti)
#pragma unroll
    for (int tj = 0; tj < 4; ++tj) {
      const int krel = wk + tj * 16 + col;
      const float eq = esq_s[krel];
#pragma unroll
      for (int r = 0; r < 4; ++r) {
        const int nl = wn + ti * 16 + quad * 4 + r;
        const float d = (xsq_s[nl] + eq) - 2.f * acc[ti][tj][r];
        if (d <= thr_s[nl]) {
          const unsigned slot = atomicAdd(&cntL[nl], 1u);
          if (slot < 4u)
            cand[((size_t)(nblk + nl) * 8 + blockIdx.y) * 4 + slot] =
                (unsigned)(kblk + krel);
        }
      }
    }
  __syncthreads();
  if (t < 128) {
    unsigned c = cntL[t];
    const size_t base = ((size_t)(nblk + t) * 8 + blockIdx.y) * 4;
    if (c > 4u) { cand[base + 3] = 0xFFFFFFFEu; c = 3u; }  // overflow -> rescan
    for (unsigned s = c; s < 4u; ++s) cand[base + s] = 0xFFFFFFFFu;
  }
}

// ---------------- resolve v2: exact fp32 rescoring, worklist form -----------
// Block = 32 points, grid = NPTS/32 = 1024 (4 blocks/CU resident).
// x staged once in LDS (values identical to global -> score chain bits
// identical to R5's, which passed). Worklist bounded by 32*8*4 = 1024.
__global__ __launch_bounds__(256) void resolve_kernel(
    const float* __restrict__ x, const float* __restrict__ emb,
    const float* __restrict__ esq, const float* __restrict__ xsq,
    const float* __restrict__ part, const unsigned int* __restrict__ cand,
    int* __restrict__ idx) {
  __shared__ float xls[DIM][32];                 // 32 KB, [c][p]
  __shared__ unsigned list[1024];                // 4 KB worklist
  __shared__ unsigned long long best[32];
  __shared__ float thr_s[32], xsq_s[32];
  __shared__ int lcnt;

  const int t = threadIdx.x;
  const int n0 = blockIdx.x * 32;
  const int bb = n0 >> 10, hw0 = n0 & 1023;

  // stage x tile (coalesced; read x exactly once)
  const float* xb = x + (size_t)bb * CHW + hw0;
  {
    const int p = t & 31, cs = t >> 5;
#pragma unroll 8
    for (int r = 0; r < 32; ++r) {
      const int c = r * 8 + cs;
      xls[c][p] = xb[(size_t)c * 1024 + p];
    }
  }
  if (t == 0) lcnt = 0;
  if (t < 32) {
    best[t] = ~0ULL;
    xsq_s[t] = xsq[n0 + t];
    const float4 p0 = *(const float4*)&part[(size_t)(n0 + t) * 8];
    const float4 p1 = *(const float4*)&part[(size_t)(n0 + t) * 8 + 4];
    float g = fminf(fminf(fminf(p0.x, p0.y), fminf(p0.z, p0.w)),
                    fminf(fminf(p1.x, p1.y), fminf(p1.z, p1.w)));
    thr_s[t] = g + MARGIN;
  }
  __syncthreads();

  // build worklist: thread t handles (point nn = t>>3, split s = t&7)
  {
    const int nn = t >> 3, s = t & 7;
    const float pv = part[(size_t)(n0 + nn) * 8 + s];
    if (pv <= thr_s[nn]) {
      const uint4 c4 = *(const uint4*)&cand[((size_t)(n0 + nn) * 8 + s) * 4];
      const unsigned vs[4] = {c4.x, c4.y, c4.z, c4.w};
#pragma unroll
      for (int i = 0; i < 4; ++i) {
        const unsigned v = vs[i];
        if (v == 0xFFFFFFFFu) continue;
        const unsigned entry = (v == 0xFFFFFFFEu)
                                   ? ((unsigned)nn << 11) | 1024u | (unsigned)s
                                   : ((unsigned)nn << 11) | (v & 1023u);
        const int pos = atomicAdd(&lcnt, 1);
        if (pos < 1024) list[pos] = entry;   // bound: 32*8*4 = 1024
      }
    }
  }
  __syncthreads();

  // consume worklist; score chain bit-identical to R5 (fmaf, c ascending)
  const int L = lcnt < 1024 ? lcnt : 1024;
  for (int e = t; e < L; e += 256) {
    const unsigned entry = list[e];
    const int p = entry >> 11;
    const float xq = xsq_s[p];
    int klo, khi;
    if (entry & 1024u) { const int s = entry & 7; klo = s * 128; khi = klo + 128; }
    else               { klo = entry & 1023u; khi = klo + 1; }
    for (int k = klo; k < khi; ++k) {
      const float* er = emb + (size_t)k * DIM;
      float dot = 0.f;
#pragma unroll 4
      for (int c4 = 0; c4 < DIM; c4 += 4) {
        const float4 e4 = *(const float4*)(er + c4);
        dot = fmaf(xls[c4 + 0][p], e4.x, dot);
        dot = fmaf(xls[c4 + 1][p], e4.y, dot);
        dot = fmaf(xls[c4 + 2][p], e4.z, dot);
        dot = fmaf(xls[c4 + 3][p], e4.w, dot);
      }
      const float t1 = xq + esq[k];
      const float d = t1 - 2.f * dot;
      const unsigned long long key =
          ((unsigned long long)__float_as_uint(d) << 32) | (unsigned)k;
      atomicMin(&best[p], key);   // d>0 -> uint-monotone; low k wins ties
    }
  }
  __syncthreads();
  if (t < 32) idx[n0 + t] = (int)(best[t] & 0xFFFFFFFFu);
}

// ------- fused: quantized gather+write, loss, one-hot (R4 structure) --------
__global__ __launch_bounds__(256) void quant_enc_kernel(
    const float* __restrict__ x, const float* __restrict__ emb,
    const int* __restrict__ idx, float* __restrict__ outq,
    float* __restrict__ enc, float* __restrict__ loss) {
  __shared__ float tile[DIM * 32];   // 32 KB, [c][p]
  __shared__ int ids[32];
  __shared__ float lred[4];
  const int t = threadIdx.x;
  const int n0 = blockIdx.x * 32;    // grid = NPTS/32 = 1024
  const int bb = n0 >> 10, hw0 = n0 & 1023;

  if (t < 32) ids[t] = idx[n0 + t];
  __syncthreads();

  const int p = t & 31, cseg = t >> 5;
  const int row = ids[p];
  const float* er = emb + (size_t)row * DIM + cseg * 32;
#pragma unroll
  for (int i = 0; i < 8; ++i) {
    const float4 v = *(const float4*)(er + i * 4);
    const int c = cseg * 32 + i * 4;
    tile[(c + 0) * 32 + p] = v.x;
    tile[(c + 1) * 32 + p] = v.y;
    tile[(c + 2) * 32 + p] = v.z;
    tile[(c + 3) * 32 + p] = v.w;
  }
  __syncthreads();

  float lsum = 0.f;
  const float* xb = x + (size_t)bb * CHW + hw0;
  float* ob = outq + (size_t)bb * CHW + hw0;
#pragma unroll
  for (int i = 0; i < 32; ++i) {
    const int c = cseg + i * 8;
    const float q  = tile[c * 32 + p];
    const float xv = xb[(size_t)c * 1024 + p];
    ob[(size_t)c * 1024 + p] = q;    // outq only 4B-aligned -> scalar, coalesced
    const float d = q - xv;
    lsum = fmaf(d, d, lsum);
  }
  float s = lsum;
#pragma unroll
  for (int o = 32; o > 0; o >>= 1) s += __shfl_down(s, o, 64);
  if ((t & 63) == 0) lred[t >> 6] = s;

#pragma unroll 4
  for (int r = 0; r < 32; ++r) {
    const int id = ids[r];
    const int kb = t * 4;
    float* eb = enc + (size_t)(n0 + r) * K + kb;
    eb[0] = (kb + 0 == id) ? 1.f : 0.f;
    eb[1] = (kb + 1 == id) ? 1.f : 0.f;
    eb[2] = (kb + 2 == id) ? 1.f : 0.f;
    eb[3] = (kb + 3 == id) ? 1.f : 0.f;
  }

  __syncthreads();
  if (t == 0) {
    const float tot = (lred[0] + lred[1] + lred[2] + lred[3]) * (1.25f / (float)QELEMS);
    atomicAdd(loss, tot);   // loss = q_latent + 0.25*e_latent = 1.25 * MSE
  }
}

extern "C" void kernel_launch(void* const* d_in, const int* in_sizes, int n_in,
                              void* d_out, int out_size, void* d_ws, size_t ws_size,
                              hipStream_t stream) {
  const float* x   = (const float*)d_in[0];
  const float* emb = (const float*)d_in[1];
  float* out  = (float*)d_out;
  float* loss = out;                       // [1]
  float* outq = out + 1;                   // [8388608], 4B-aligned only
  float* enc  = out + 1 + QELEMS;          // [33554432], 4B-aligned only

  char* ws = (char*)d_ws;
  unsigned short* ehi  = (unsigned short*)ws;                  // 512 KB
  float*          esq  = (float*)(ws + 524288);                // 4 KB
  float*          xsq  = (float*)(ws + 528384);                // 128 KB
  int*            idx  = (int*)(ws + 659456);                  // 128 KB
  float*          part = (float*)(ws + 790528);                // 1 MB
  unsigned int*   cand = (unsigned int*)(ws + 1839104);        // 4 MB
  unsigned short* xhi  = (unsigned short*)(ws + 6033408);      // 16 MB
  // total ws use: ~22.8 MB

  hipMemsetAsync(loss, 0, sizeof(float), stream);

  eprep_kernel<<<K / 64, 256, 0, stream>>>(emb, ehi, esq);
  xprep_kernel<<<NPTS / 64, 256, 0, stream>>>(x, xhi, xsq);
  dim3 cg(NPTS / 128, 8);
  coarse_kernel<<<cg, 256, 0, stream>>>(xhi, ehi, esq, xsq, part, cand);
  resolve_kernel<<<NPTS / 32, 256, 0, stream>>>(x, emb, esq, xsq, part, cand, idx);
  quant_enc_kernel<<<NPTS / 32, 256, 0, stream>>>(x, emb, idx, outq, enc, loss);
}